// Round 1
// baseline (86.910 us; speedup 1.0000x reference)
//
#include <hip/hip_runtime.h>

#define MAX_BS 128
#define INV4PI 0.07957747154594767f

// One WAVE per pair (u,q): lane t owns target rows t and t+64.
// Two pairs per 128-thread block (keeps 32 waves/CU; 64-thread blocks would
// halve occupancy via the per-CU workgroup cap).
// Source box (Xq rows + q_vec) is wave-uniform -> scalar pipe (s_load
// broadcasts into SGPRs): no LDS, no barrier. Row-pairing means each pair's
// uniform scalar stream is loaded ONCE (previously ~1.48 waves/pair each
// streamed it independently), and loop control is shared across 2 rows.
template<bool TWO, bool SELF>
__device__ __forceinline__ void body(
    const float* __restrict__ Xq, const float* __restrict__ qv,
    const int bs_q,
    const float xu0, const float yu0, const float zu0,
    const float xu1, const float yu1, const float zu1,
    float& acc0, float& acc1)
{
#pragma unroll 8
    for (int j = 0; j < bs_q; ++j) {
        const float sx = Xq[3 * j + 0];   // uniform -> s_load, free bcast
        const float sy = Xq[3 * j + 1];
        const float sz = Xq[3 * j + 2];
        const float w  = qv[j];

        // Row 0 (target t)
        const float dx0 = xu0 - sx;
        const float dy0 = yu0 - sy;
        const float dz0 = zu0 - sz;
        const float r20 = dx0 * dx0 + dy0 * dy0 + dz0 * dz0;
        float ri0 = __builtin_amdgcn_rsqf(r20);
        if (SELF) ri0 = (r20 > 0.0f) ? ri0 : 0.0f;   // mask exact self-hit
        acc0 = fmaf(w, ri0, acc0);

        // Row 1 (target t+64), only when bs_u > 64 (wave-uniform branch)
        if (TWO) {
            const float dx1 = xu1 - sx;
            const float dy1 = yu1 - sy;
            const float dz1 = zu1 - sz;
            const float r21 = dx1 * dx1 + dy1 * dy1 + dz1 * dz1;
            float ri1 = __builtin_amdgcn_rsqf(r21);
            if (SELF) ri1 = (r21 > 0.0f) ? ri1 : 0.0f;
            acc1 = fmaf(w, ri1, acc1);
        }
    }
}

__global__ __launch_bounds__(128) void fmm_wave_kernel(
    const float* __restrict__ q_vec,    // [NBOXES][MAX_BS]
    const float* __restrict__ XX,       // [NBOXES][MAX_BS][3]
    const int*   __restrict__ bs_list,  // [NBOXES]
    const int2*  __restrict__ uq_boxes, // [NPAIRS]
    float*       __restrict__ out,      // [NBOXES][MAX_BS]
    const int npairs)
{
    const int wv = threadIdx.x >> 6;    // which pair within the block
    const int t  = threadIdx.x & 63;    // target row (and row t+64)
    const int p  = blockIdx.x * 2 + wv;
    if (p >= npairs) return;

    const int2 uq = uq_boxes[p];
    // Force uniform -> SGPR so all derived addresses are scalar.
    const int u = __builtin_amdgcn_readfirstlane(uq.x);
    const int q = __builtin_amdgcn_readfirstlane(uq.y);
    const int bs_u = bs_list[u];        // uniform -> s_load
    const int bs_q = bs_list[q];

    if (t >= bs_u || bs_q == 0) return; // row1 active implies t < bs_u - 64,
                                        // so this exit is exact for both rows

    // Own target point(s) (vector loads, lane-varying).
    const float* __restrict__ Xu = XX + (size_t)u * (MAX_BS * 3);
    const float xu0 = Xu[3 * t + 0];
    const float yu0 = Xu[3 * t + 1];
    const float zu0 = Xu[3 * t + 2];

    const bool two = (bs_u > 64);       // wave-uniform predicate
    float xu1 = 0.0f, yu1 = 0.0f, zu1 = 0.0f;
    if (two) {
        // Row t+64 always in-bounds memory-wise (MAX_BS=128 rows allocated);
        // lanes with t+64 >= bs_u compute garbage that is never stored
        // (same wasted-lane fraction as the old half-empty second wave).
        xu1 = Xu[3 * (t + 64) + 0];
        yu1 = Xu[3 * (t + 64) + 1];
        zu1 = Xu[3 * (t + 64) + 2];
    }

    // Uniform source pointers -> scalar loads inside the loop.
    const float* __restrict__ Xq = XX + (size_t)q * (MAX_BS * 3);
    const float* __restrict__ qv = q_vec + (size_t)q * MAX_BS;

    float acc0 = 0.0f, acc1 = 0.0f;
    if (u != q) {
        // Distinct boxes: r2 > 0 always (continuous random coords).
        if (two) body<true , false>(Xq, qv, bs_q, xu0, yu0, zu0, xu1, yu1, zu1, acc0, acc1);
        else     body<false, false>(Xq, qv, bs_q, xu0, yu0, zu0, xu1, yu1, zu1, acc0, acc1);
    } else {
        // Self pair (~2 of 8192): mask exact self-interaction via r2 > 0.
        if (two) body<true , true >(Xq, qv, bs_q, xu0, yu0, zu0, xu1, yu1, zu1, acc0, acc1);
        else     body<false, true >(Xq, qv, bs_q, xu0, yu0, zu0, xu1, yu1, zu1, acc0, acc1);
    }

    // INV4PI hoisted out of the loop (w was raw q_vec).
    float* __restrict__ orow = out + (size_t)u * MAX_BS;
    atomicAdd(orow + t, acc0 * INV4PI);
    if (two && (t + 64 < bs_u)) atomicAdd(orow + t + 64, acc1 * INV4PI);
}

extern "C" void kernel_launch(void* const* d_in, const int* in_sizes, int n_in,
                              void* d_out, int out_size, void* d_ws, size_t ws_size,
                              hipStream_t stream) {
    const float* q_vec    = (const float*)d_in[0];
    const float* XX_list  = (const float*)d_in[1];
    const int*   bs_list  = (const int*)d_in[2];
    const int2*  uq_boxes = (const int2*)d_in[3];
    float* out = (float*)d_out;

    const int npairs = in_sizes[3] / 2;   // 8192

    // Atomic accumulation needs a zeroed output (harness poisons with 0xAA).
    hipMemsetAsync(d_out, 0, (size_t)out_size * sizeof(float), stream);

    const int nblocks = (npairs + 1) / 2; // 2 pairs (waves) per 128-thr block
    fmm_wave_kernel<<<nblocks, 128, 0, stream>>>(
        q_vec, XX_list, bs_list, uq_boxes, out, npairs);
}